// Round 6
// baseline (103.002 us; speedup 1.0000x reference)
//
#include <hip/hip_runtime.h>
#include <math.h>

#define LNEPS 1e-5f

typedef short bf16x8 __attribute__((ext_vector_type(8)));
typedef float f32x4 __attribute__((ext_vector_type(4)));

__device__ __forceinline__ unsigned short f2bf(float f) {
    union { float f; unsigned int u; } v; v.f = f;
    unsigned int r = v.u + 0x7fffu + ((v.u >> 16) & 1u);
    return (unsigned short)(r >> 16);
}

__device__ __forceinline__ void block_ln_stats(float v, int tid, float* red,
                                               float& mu, float& rs) {
    float s = v, ss = v * v;
#pragma unroll
    for (int off = 32; off; off >>= 1) {
        s += __shfl_xor(s, off);
        ss += __shfl_xor(ss, off);
    }
    if ((tid & 63) == 0) { red[tid >> 6] = s; red[4 + (tid >> 6)] = ss; }
    __syncthreads();
    s = red[0] + red[1] + red[2] + red[3];
    ss = red[4] + red[5] + red[6] + red[7];
    mu = s * (1.0f / 256.0f);
    float var = ss * (1.0f / 256.0f) - mu * mu;
    rs = rsqrtf(var + LNEPS);
}

__device__ __forceinline__ float gelu_exact(float v) {
    return 0.5f * v * (1.0f + erff(v * 0.70710678118654752f));
}

// ---------- kATT: fused [LN_mia + V = xn@Wv] + [W1,W2 transpose->bf16] ----------
__global__ __launch_bounds__(256) void kATT(const float* __restrict__ x,
                                            const float* __restrict__ g,
                                            const float* __restrict__ be,
                                            const float* __restrict__ Wv,
                                            float* __restrict__ V,
                                            const float* __restrict__ W1,
                                            unsigned short* __restrict__ W1t,
                                            const float* __restrict__ W2,
                                            unsigned short* __restrict__ W2t) {
    __shared__ float smem[32 * 33];
    const int bid = blockIdx.x, tid = threadIdx.x;
    if (bid < 4096) {
        float* sx = smem;
        float* red = smem + 256;
        float* part = smem + 264;
        const int token = bid;
        float v = x[(size_t)token * 256 + tid];
        float mu, rs;
        block_ln_stats(v, tid, red, mu, rs);
        sx[tid] = (v - mu) * rs * g[tid] + be[tid];
        __syncthreads();
        const int c = tid & 63, q = tid >> 6;
        float p = 0.f;
        const float* wp = Wv + (size_t)(q * 64) * 64 + c;
#pragma unroll 8
        for (int d = 0; d < 64; ++d) p = fmaf(sx[q * 64 + d], wp[(size_t)d * 64], p);
        part[q * 64 + c] = p;
        __syncthreads();
        if (tid < 64)
            V[(size_t)token * 64 + tid] =
                part[tid] + part[64 + tid] + part[128 + tid] + part[192 + tid];
    } else {
        int b = bid - 4096;
        const float* W;
        unsigned short* Wt;
        int K, N, n0, k0;
        if (b < 256) { W = W1; Wt = W1t; K = 256; N = 1024; n0 = (b & 31) * 32; k0 = (b >> 5) * 32; }
        else { b -= 256; W = W2; Wt = W2t; K = 1024; N = 256; n0 = (b & 7) * 32; k0 = (b >> 3) * 32; }
        float(*s)[33] = (float(*)[33])smem;
        const int cl = tid & 31, rq = tid >> 5;
#pragma unroll
        for (int i = 0; i < 4; ++i)
            s[rq * 4 + i][cl] = W[(size_t)(k0 + rq * 4 + i) * N + n0 + cl];
        __syncthreads();
#pragma unroll
        for (int i = 0; i < 4; ++i)
            Wt[(size_t)(n0 + rq * 4 + i) * K + k0 + cl] = f2bf(s[cl][rq * 4 + i]);
    }
}

// ---------- kernel B: no-max softmax MIA + @Wo + residual + LN_ffn ----------
// Writes d_out = x2 + b2 (fully overwritten each call -> replay-idempotent;
// kFFN accumulates the FFN GEMM2 result on top, each element owned by 1 thread).
__global__ __launch_bounds__(256) void kB(const float* __restrict__ x,
                                          const float4* __restrict__ U4,
                                          const int* __restrict__ mask,
                                          const float4* __restrict__ V4,
                                          const float* __restrict__ Wo,
                                          const float* __restrict__ gf,
                                          const float* __restrict__ bf,
                                          const float* __restrict__ b2,
                                          float* __restrict__ out,
                                          unsigned short* __restrict__ xn2b) {
    __shared__ float sl[16][64], al[16][64];
    __shared__ float mia[64];
    __shared__ float red[8];
    __shared__ float mkf[256];
    const int token = blockIdx.x, tid = threadIdx.x;
    const int b = token >> 8;
    const int l16 = tid & 15, jo = tid >> 4;
    mkf[tid] = (mask[b * 256 + tid] != 0) ? 1.0f : 0.0f;
    __syncthreads();

    float s0 = 0, s1 = 0, s2 = 0, s3 = 0;
    float a0 = 0, a1 = 0, a2 = 0, a3 = 0;
    const size_t ub = (size_t)token * (256 * 16);
    const size_t vb = (size_t)b * (256 * 16);
#pragma unroll 4
    for (int j = jo; j < 256; j += 16) {
        float4 u = U4[ub + (size_t)j * 16 + l16];
        float4 vv = V4[vb + (size_t)j * 16 + l16];
        float mw = mkf[j];
        float w;
        w = __expf(u.x) * mw; s0 += w; a0 = fmaf(w, vv.x, a0);
        w = __expf(u.y) * mw; s1 += w; a1 = fmaf(w, vv.y, a1);
        w = __expf(u.z) * mw; s2 += w; a2 = fmaf(w, vv.z, a2);
        w = __expf(u.w) * mw; s3 += w; a3 = fmaf(w, vv.w, a3);
    }
    sl[jo][l16 * 4 + 0] = s0; sl[jo][l16 * 4 + 1] = s1;
    sl[jo][l16 * 4 + 2] = s2; sl[jo][l16 * 4 + 3] = s3;
    al[jo][l16 * 4 + 0] = a0; al[jo][l16 * 4 + 1] = a1;
    al[jo][l16 * 4 + 2] = a2; al[jo][l16 * 4 + 3] = a3;
    __syncthreads();
    if (tid < 64) {
        float S = 0, A = 0;
#pragma unroll
        for (int p = 0; p < 16; ++p) { S += sl[p][tid]; A += al[p][tid]; }
        mia[tid] = A / S;
    }
    __syncthreads();

    float r = x[(size_t)token * 256 + tid];
#pragma unroll 8
    for (int c = 0; c < 64; ++c) r = fmaf(mia[c], Wo[(size_t)c * 256 + tid], r);
    out[(size_t)token * 256 + tid] = r + b2[tid];
    float mu, rs;
    block_ln_stats(r, tid, red, mu, rs);
    xn2b[(size_t)token * 256 + tid] = f2bf((r - mu) * rs * gf[tid] + bf[tid]);
}

// ---------- kFFN: fused FFN. Per block: 16-row strip, full F loop. ----------
// out[strip] += gelu(xn2b[strip] @ W1 + b1) @ W2   (out pre-seeded = x2 + b2 by kB)
// Weights streamed from L2 per F-chunk of 64. 256 blocks, 256 threads (4 waves).
__global__ __launch_bounds__(256) void kFFN(const unsigned short* __restrict__ xn2b,
                                            const unsigned short* __restrict__ W1t,
                                            const unsigned short* __restrict__ W2t,
                                            const float* __restrict__ b1,
                                            float* __restrict__ out) {
    __shared__ __align__(16) unsigned short sXn[16][264];  // 8448 B
    __shared__ __align__(16) unsigned short sW1[64][264];  // 33792 B
    __shared__ __align__(16) unsigned short sW2[256][72];  // 36864 B
    __shared__ __align__(16) unsigned short sH[16][72];    // 2304 B
    const int tid = threadIdx.x;
    const int t0 = blockIdx.x * 16;
    const int w = tid >> 6, lane = tid & 63;
    const int fr = lane & 15, fg = lane >> 4;

    // stage xn strip once: 16 rows x 256 bf16 = 512 uint4
#pragma unroll
    for (int h = 0; h < 2; ++h) {
        int idx = tid + h * 256;
        int row = idx >> 5, seg = idx & 31;
        *(uint4*)&sXn[row][seg * 8] =
            *(const uint4*)&xn2b[(size_t)(t0 + row) * 256 + seg * 8];
    }

    f32x4 acc2[4] = {};  // out cols w*64 .. w*64+63, accumulated over all chunks
    for (int ch = 0; ch < 16; ++ch) {
        const int c0 = ch * 64;   // F-chunk base
        // stage W1 chunk: rows c0..c0+63 of W1t[1024][256] -> 2048 uint4
#pragma unroll
        for (int h = 0; h < 8; ++h) {
            int idx = tid + h * 256;
            int row = idx >> 5, seg = idx & 31;
            *(uint4*)&sW1[row][seg * 8] =
                *(const uint4*)&W1t[(size_t)(c0 + row) * 256 + seg * 8];
        }
        // stage W2 chunk: K-slice c0..c0+63 of W2t[256][1024] -> 2048 uint4
#pragma unroll
        for (int h = 0; h < 8; ++h) {
            int idx = tid + h * 256;
            int row = idx >> 3, seg = idx & 7;
            *(uint4*)&sW2[row][seg * 8] =
                *(const uint4*)&W2t[(size_t)row * 1024 + c0 + seg * 8];
        }
        __syncthreads();

        // GEMM1: H[16][64] = xn[16][256] @ W1c^T ; wave w does cols w*16..+15
        f32x4 h1a = {}, h1b = {};
#pragma unroll
        for (int ks = 0; ks < 8; ks += 2) {
            bf16x8 a0 = *(const bf16x8*)&sXn[fr][ks * 32 + fg * 8];
            bf16x8 b0 = *(const bf16x8*)&sW1[w * 16 + fr][ks * 32 + fg * 8];
            bf16x8 a1 = *(const bf16x8*)&sXn[fr][(ks + 1) * 32 + fg * 8];
            bf16x8 b1f = *(const bf16x8*)&sW1[w * 16 + fr][(ks + 1) * 32 + fg * 8];
            h1a = __builtin_amdgcn_mfma_f32_16x16x32_bf16(a0, b0, h1a, 0, 0, 0);
            h1b = __builtin_amdgcn_mfma_f32_16x16x32_bf16(a1, b1f, h1b, 0, 0, 0);
        }
        float bb = b1[c0 + w * 16 + fr];
#pragma unroll
        for (int r = 0; r < 4; ++r)
            sH[fg * 4 + r][w * 16 + fr] = f2bf(gelu_exact(h1a[r] + h1b[r] + bb));
        __syncthreads();

        // GEMM2: acc2 += H[16][64] @ W2c ; wave w does out cols w*64..+63
#pragma unroll
        for (int k2 = 0; k2 < 2; ++k2) {
            bf16x8 a = *(const bf16x8*)&sH[fr][k2 * 32 + fg * 8];
#pragma unroll
            for (int q = 0; q < 4; ++q) {
                bf16x8 b = *(const bf16x8*)&sW2[w * 64 + q * 16 + fr][k2 * 32 + fg * 8];
                acc2[q] = __builtin_amdgcn_mfma_f32_16x16x32_bf16(a, b, acc2[q], 0, 0, 0);
            }
        }
        __syncthreads();  // protect sW1/sW2/sH before next chunk's staging
    }

    // epilogue: out += acc2 (each element owned by exactly one thread)
#pragma unroll
    for (int q = 0; q < 4; ++q) {
        int col = w * 64 + q * 16 + fr;
#pragma unroll
        for (int r = 0; r < 4; ++r) {
            int row = t0 + fg * 4 + r;
            size_t idx = (size_t)row * 256 + col;
            out[idx] += acc2[q][r];
        }
    }
}

extern "C" void kernel_launch(void* const* d_in, const int* in_sizes, int n_in,
                              void* d_out, int out_size, void* d_ws, size_t ws_size,
                              hipStream_t stream) {
    const float* x = (const float*)d_in[0];
    const float* U1 = (const float*)d_in[1];
    const int* mask = (const int*)d_in[2];
    const float* ln_mia_g = (const float*)d_in[3];
    const float* ln_mia_b = (const float*)d_in[4];
    const float* Wv = (const float*)d_in[5];
    const float* Wo = (const float*)d_in[6];
    const float* ln_ffn_g = (const float*)d_in[7];
    const float* ln_ffn_b = (const float*)d_in[8];
    const float* W1 = (const float*)d_in[9];
    const float* b1 = (const float*)d_in[10];
    const float* W2 = (const float*)d_in[11];
    const float* b2 = (const float*)d_in[12];
    float* out = (float*)d_out;

    char* ws = (char*)d_ws;
    float* V             = (float*)(ws);                                      // 1 MB
    unsigned short* xn2b = (unsigned short*)(ws + (1u << 20));                // 2 MB
    unsigned short* W1t  = (unsigned short*)(ws + (3u << 20));                // 512 KB
    unsigned short* W2t  = (unsigned short*)(ws + (3u << 20) + (512u << 10)); // 512 KB

    kATT<<<4608, 256, 0, stream>>>(x, ln_mia_g, ln_mia_b, Wv, V, W1, W1t, W2, W2t);
    kB<<<4096, 256, 0, stream>>>(x, (const float4*)U1, mask, (const float4*)V,
                                 Wo, ln_ffn_g, ln_ffn_b, b2, out, xn2b);
    kFFN<<<256, 256, 0, stream>>>(xn2b, W1t, W2t, b1, out);
}

// Round 7
// 82.164 us; speedup vs baseline: 1.2536x; 1.2536x over previous
//
#include <hip/hip_runtime.h>
#include <math.h>

#define LNEPS 1e-5f

typedef short bf16x8 __attribute__((ext_vector_type(8)));
typedef float f32x4 __attribute__((ext_vector_type(4)));

__device__ __forceinline__ unsigned short f2bf(float f) {
    union { float f; unsigned int u; } v; v.f = f;
    unsigned int r = v.u + 0x7fffu + ((v.u >> 16) & 1u);
    return (unsigned short)(r >> 16);
}

__device__ __forceinline__ float bf2f(unsigned short u) {
    union { unsigned int i; float f; } v;
    v.i = ((unsigned int)u) << 16;
    return v.f;
}

__device__ __forceinline__ void block_ln_stats(float v, int tid, float* red,
                                               float& mu, float& rs) {
    float s = v, ss = v * v;
#pragma unroll
    for (int off = 32; off; off >>= 1) {
        s += __shfl_xor(s, off);
        ss += __shfl_xor(ss, off);
    }
    if ((tid & 63) == 0) { red[tid >> 6] = s; red[4 + (tid >> 6)] = ss; }
    __syncthreads();
    s = red[0] + red[1] + red[2] + red[3];
    ss = red[4] + red[5] + red[6] + red[7];
    mu = s * (1.0f / 256.0f);
    float var = ss * (1.0f / 256.0f) - mu * mu;
    rs = rsqrtf(var + LNEPS);
}

__device__ __forceinline__ float gelu_exact(float v) {
    return 0.5f * v * (1.0f + erff(v * 0.70710678118654752f));
}

// ---------- kATT: [kA 8-tok: LN_mia + V=xn@Wv ->bf16] + [W1,W2 transp->bf16] + [Wo->bf16]
__global__ __launch_bounds__(256) void kATT(const float* __restrict__ x,
                                            const float* __restrict__ g,
                                            const float* __restrict__ be,
                                            const float* __restrict__ Wv,
                                            unsigned short* __restrict__ Vb,
                                            const float* __restrict__ W1,
                                            unsigned short* __restrict__ W1t,
                                            const float* __restrict__ W2,
                                            unsigned short* __restrict__ W2t,
                                            const float* __restrict__ Wo,
                                            unsigned short* __restrict__ Wob) {
    __shared__ float smem[4096];
    const int bid = blockIdx.x, tid = threadIdx.x;
    if (bid < 512) {
        // kA: tokens t0..t0+7
        float* sx = smem;           // [8][256]
        float* part = smem + 2048;  // [4][8][64]
        const int t0 = bid * 8;
        {
            const int r = tid >> 5, lc = tid & 31;
            const float* xr = x + (size_t)(t0 + r) * 256 + lc * 8;
            float vv[8];
            *(float4*)&vv[0] = *(const float4*)xr;
            *(float4*)&vv[4] = *(const float4*)(xr + 4);
            float s = 0.f, ss = 0.f;
#pragma unroll
            for (int i = 0; i < 8; ++i) { s += vv[i]; ss = fmaf(vv[i], vv[i], ss); }
#pragma unroll
            for (int off = 16; off; off >>= 1) {
                s += __shfl_xor(s, off, 32);
                ss += __shfl_xor(ss, off, 32);
            }
            float mu = s * (1.0f / 256.0f);
            float var = ss * (1.0f / 256.0f) - mu * mu;
            float rs = rsqrtf(var + LNEPS);
            const int c0 = lc * 8;
            float o[8];
#pragma unroll
            for (int i = 0; i < 8; ++i)
                o[i] = (vv[i] - mu) * rs * g[c0 + i] + be[c0 + i];
            *(float4*)&sx[r * 256 + c0] = *(float4*)&o[0];
            *(float4*)&sx[r * 256 + c0 + 4] = *(float4*)&o[4];
        }
        __syncthreads();
        const int c = tid & 63, q = tid >> 6;
        float p[8] = {};
        const float* wp = Wv + (size_t)(q * 64) * 64 + c;
        const float* sxp = sx + q * 64;
#pragma unroll 8
        for (int d = 0; d < 64; ++d) {
            float wv = wp[(size_t)d * 64];
#pragma unroll
            for (int r = 0; r < 8; ++r) p[r] = fmaf(sxp[r * 256 + d], wv, p[r]);
        }
#pragma unroll
        for (int r = 0; r < 8; ++r) part[(q * 8 + r) * 64 + c] = p[r];
        __syncthreads();
        const int rr = tid >> 6;
#pragma unroll
        for (int rw = rr; rw < 8; rw += 4) {
            float sum = part[(0 * 8 + rw) * 64 + c] + part[(1 * 8 + rw) * 64 + c] +
                        part[(2 * 8 + rw) * 64 + c] + part[(3 * 8 + rw) * 64 + c];
            Vb[(size_t)(t0 + rw) * 64 + c] = f2bf(sum);
        }
    } else if (bid < 1024) {
        int b = bid - 512;
        const float* W;
        unsigned short* Wt;
        int K, N, n0, k0;
        if (b < 256) { W = W1; Wt = W1t; K = 256; N = 1024; n0 = (b & 31) * 32; k0 = (b >> 5) * 32; }
        else { b -= 256; W = W2; Wt = W2t; K = 1024; N = 256; n0 = (b & 7) * 32; k0 = (b >> 3) * 32; }
        float(*s)[33] = (float(*)[33])smem;
        const int cl = tid & 31, rq = tid >> 5;
#pragma unroll
        for (int i = 0; i < 4; ++i)
            s[rq * 4 + i][cl] = W[(size_t)(k0 + rq * 4 + i) * N + n0 + cl];
        __syncthreads();
#pragma unroll
        for (int i = 0; i < 4; ++i)
            Wt[(size_t)(n0 + rq * 4 + i) * K + k0 + cl] = f2bf(s[cl][rq * 4 + i]);
    } else {
        // Wo [64][256] f32 -> bf16 (same layout). 8 blocks x 256 thr x 8 elems.
        int i = ((bid - 1024) * 256 + tid) * 8;
        float4 a = *(const float4*)&Wo[i];
        float4 d = *(const float4*)&Wo[i + 4];
        ushort4 o1, o2;
        o1.x = f2bf(a.x); o1.y = f2bf(a.y); o1.z = f2bf(a.z); o1.w = f2bf(a.w);
        o2.x = f2bf(d.x); o2.y = f2bf(d.y); o2.z = f2bf(d.z); o2.w = f2bf(d.w);
        *(ushort4*)&Wob[i] = o1;
        *(ushort4*)&Wob[i + 4] = o2;
    }
}

// ---------- kernel B: no-max softmax MIA + @Wo + residual + LN_ffn ----------
// Writes d_out = x2 + b2 (fully overwritten -> replay-idempotent; kC3m adds on top).
__global__ __launch_bounds__(256) void kB(const float* __restrict__ x,
                                          const float4* __restrict__ U4,
                                          const int* __restrict__ mask,
                                          const ushort4* __restrict__ V4b,
                                          const unsigned short* __restrict__ Wob,
                                          const float* __restrict__ gf,
                                          const float* __restrict__ bf,
                                          const float* __restrict__ b2,
                                          float* __restrict__ out,
                                          unsigned short* __restrict__ xn2b) {
    __shared__ float sl[16][64], al[16][64];
    __shared__ float mia[64];
    __shared__ float red[8];
    __shared__ float mkf[256];
    const int token = blockIdx.x, tid = threadIdx.x;
    const int b = token >> 8;
    const int l16 = tid & 15, jo = tid >> 4;
    mkf[tid] = (mask[b * 256 + tid] != 0) ? 1.0f : 0.0f;
    __syncthreads();

    float s0 = 0, s1 = 0, s2 = 0, s3 = 0;
    float a0 = 0, a1 = 0, a2 = 0, a3 = 0;
    const size_t ub = (size_t)token * (256 * 16);
    const size_t vb = (size_t)b * (256 * 16);
#pragma unroll 4
    for (int j = jo; j < 256; j += 16) {
        float4 u = U4[ub + (size_t)j * 16 + l16];
        ushort4 vv4 = V4b[vb + (size_t)j * 16 + l16];
        float mw = mkf[j];
        float w;
        w = __expf(u.x) * mw; s0 += w; a0 = fmaf(w, bf2f(vv4.x), a0);
        w = __expf(u.y) * mw; s1 += w; a1 = fmaf(w, bf2f(vv4.y), a1);
        w = __expf(u.z) * mw; s2 += w; a2 = fmaf(w, bf2f(vv4.z), a2);
        w = __expf(u.w) * mw; s3 += w; a3 = fmaf(w, bf2f(vv4.w), a3);
    }
    sl[jo][l16 * 4 + 0] = s0; sl[jo][l16 * 4 + 1] = s1;
    sl[jo][l16 * 4 + 2] = s2; sl[jo][l16 * 4 + 3] = s3;
    al[jo][l16 * 4 + 0] = a0; al[jo][l16 * 4 + 1] = a1;
    al[jo][l16 * 4 + 2] = a2; al[jo][l16 * 4 + 3] = a3;
    __syncthreads();
    if (tid < 64) {
        float S = 0, A = 0;
#pragma unroll
        for (int p = 0; p < 16; ++p) { S += sl[p][tid]; A += al[p][tid]; }
        mia[tid] = A / S;
    }
    __syncthreads();

    float r = x[(size_t)token * 256 + tid];
#pragma unroll 8
    for (int c = 0; c < 64; ++c)
        r = fmaf(mia[c], bf2f(Wob[(size_t)c * 256 + tid]), r);
    out[(size_t)token * 256 + tid] = r + b2[tid];
    float mu, rs;
    block_ln_stats(r, tid, red, mu, rs);
    xn2b[(size_t)token * 256 + tid] = f2bf((r - mu) * rs * gf[tid] + bf[tid]);
}

// ---------- kC2m: Aact = gelu(xn2b @ W1 + b1), bf16 MFMA, BK=64 ----------
__global__ __launch_bounds__(256) void kC2m(const unsigned short* __restrict__ A,
                                            const unsigned short* __restrict__ Bt,
                                            const float* __restrict__ b1,
                                            unsigned short* __restrict__ Aact) {
    __shared__ __align__(16) unsigned short As[128][72];
    __shared__ __align__(16) unsigned short Bs[64][72];
    const int tid = threadIdx.x;
    const int tileM = blockIdx.y * 128, tileN = blockIdx.x * 64;
    const int w = tid >> 6, lane = tid & 63;
    const int waveM = w >> 1, waveN = w & 1;
    const int fr = lane & 15, fg = lane >> 4;
    f32x4 acc[4][2] = {};
    for (int kc = 0; kc < 256; kc += 64) {
#pragma unroll
        for (int h = 0; h < 4; ++h) {
            int idx = tid + h * 256;
            int row = idx >> 3, seg = idx & 7;
            *(uint4*)&As[row][seg * 8] =
                *(const uint4*)&A[(size_t)(tileM + row) * 256 + kc + seg * 8];
        }
#pragma unroll
        for (int h = 0; h < 2; ++h) {
            int idx = tid + h * 256;
            int row = idx >> 3, seg = idx & 7;
            *(uint4*)&Bs[row][seg * 8] =
                *(const uint4*)&Bt[(size_t)(tileN + row) * 256 + kc + seg * 8];
        }
        __syncthreads();
        bf16x8 a[4][2], b[2][2];
#pragma unroll
        for (int m = 0; m < 4; ++m)
#pragma unroll
            for (int k = 0; k < 2; ++k)
                a[m][k] = *(const bf16x8*)&As[waveM * 64 + m * 16 + fr][k * 32 + fg * 8];
#pragma unroll
        for (int n = 0; n < 2; ++n)
#pragma unroll
            for (int k = 0; k < 2; ++k)
                b[n][k] = *(const bf16x8*)&Bs[waveN * 32 + n * 16 + fr][k * 32 + fg * 8];
#pragma unroll
        for (int k = 0; k < 2; ++k)
#pragma unroll
            for (int m = 0; m < 4; ++m)
#pragma unroll
                for (int n = 0; n < 2; ++n)
                    acc[m][n] = __builtin_amdgcn_mfma_f32_16x16x32_bf16(
                        a[m][k], b[n][k], acc[m][n], 0, 0, 0);
        __syncthreads();
    }
#pragma unroll
    for (int m = 0; m < 4; ++m)
#pragma unroll
        for (int n = 0; n < 2; ++n) {
            int col = tileN + waveN * 32 + n * 16 + fr;
            float bb = b1[col];
#pragma unroll
            for (int r = 0; r < 4; ++r) {
                int row = tileM + waveM * 64 + m * 16 + fg * 4 + r;
                float v = acc[m][n][r] + bb;
                Aact[(size_t)row * 1024 + col] = f2bf(gelu_exact(v));
            }
        }
}

// ---------- kC3m: out += Aact @ W2 (split-K x2, atomicAdd), bf16 MFMA ----------
__global__ __launch_bounds__(256) void kC3m(const unsigned short* __restrict__ A,
                                            const unsigned short* __restrict__ Bt,
                                            float* __restrict__ out) {
    __shared__ __align__(16) unsigned short As[64][72];
    __shared__ __align__(16) unsigned short Bs[64][72];
    const int tid = threadIdx.x;
    const int tileM = blockIdx.y * 64, tileN = blockIdx.x * 64;
    const int k0 = blockIdx.z * 512;
    const int w = tid >> 6, lane = tid & 63;
    const int waveM = w >> 1, waveN = w & 1;
    const int fr = lane & 15, fg = lane >> 4;
    f32x4 acc[2][2] = {};
    for (int kc = k0; kc < k0 + 512; kc += 64) {
#pragma unroll
        for (int h = 0; h < 2; ++h) {
            int idx = tid + h * 256;
            int row = idx >> 3, seg = idx & 7;
            *(uint4*)&As[row][seg * 8] =
                *(const uint4*)&A[(size_t)(tileM + row) * 1024 + kc + seg * 8];
        }
#pragma unroll
        for (int h = 0; h < 2; ++h) {
            int idx = tid + h * 256;
            int row = idx >> 3, seg = idx & 7;
            *(uint4*)&Bs[row][seg * 8] =
                *(const uint4*)&Bt[(size_t)(tileN + row) * 1024 + kc + seg * 8];
        }
        __syncthreads();
        bf16x8 a[2][2], b[2][2];
#pragma unroll
        for (int m = 0; m < 2; ++m)
#pragma unroll
            for (int k = 0; k < 2; ++k)
                a[m][k] = *(const bf16x8*)&As[waveM * 32 + m * 16 + fr][k * 32 + fg * 8];
#pragma unroll
        for (int n = 0; n < 2; ++n)
#pragma unroll
            for (int k = 0; k < 2; ++k)
                b[n][k] = *(const bf16x8*)&Bs[waveN * 32 + n * 16 + fr][k * 32 + fg * 8];
#pragma unroll
        for (int k = 0; k < 2; ++k)
#pragma unroll
            for (int m = 0; m < 2; ++m)
#pragma unroll
                for (int n = 0; n < 2; ++n)
                    acc[m][n] = __builtin_amdgcn_mfma_f32_16x16x32_bf16(
                        a[m][k], b[n][k], acc[m][n], 0, 0, 0);
        __syncthreads();
    }
#pragma unroll
    for (int m = 0; m < 2; ++m)
#pragma unroll
        for (int n = 0; n < 2; ++n) {
            int col = tileN + waveN * 32 + n * 16 + fr;
#pragma unroll
            for (int r = 0; r < 4; ++r) {
                int row = tileM + waveM * 32 + m * 16 + fg * 4 + r;
                atomicAdd(&out[(size_t)row * 256 + col], acc[m][n][r]);
            }
        }
}

extern "C" void kernel_launch(void* const* d_in, const int* in_sizes, int n_in,
                              void* d_out, int out_size, void* d_ws, size_t ws_size,
                              hipStream_t stream) {
    const float* x = (const float*)d_in[0];
    const float* U1 = (const float*)d_in[1];
    const int* mask = (const int*)d_in[2];
    const float* ln_mia_g = (const float*)d_in[3];
    const float* ln_mia_b = (const float*)d_in[4];
    const float* Wv = (const float*)d_in[5];
    const float* Wo = (const float*)d_in[6];
    const float* ln_ffn_g = (const float*)d_in[7];
    const float* ln_ffn_b = (const float*)d_in[8];
    const float* W1 = (const float*)d_in[9];
    const float* b1 = (const float*)d_in[10];
    const float* W2 = (const float*)d_in[11];
    const float* b2 = (const float*)d_in[12];
    float* out = (float*)d_out;

    char* ws = (char*)d_ws;
    unsigned short* Vb   = (unsigned short*)(ws);                             // 512 KB
    unsigned short* xn2b = (unsigned short*)(ws + (1u << 20));                // 2 MB
    unsigned short* W1t  = (unsigned short*)(ws + (3u << 20));                // 512 KB
    unsigned short* W2t  = (unsigned short*)(ws + (3u << 20) + (512u << 10)); // 512 KB
    unsigned short* Wob  = (unsigned short*)(ws + (4u << 20));                // 32 KB
    unsigned short* Aact = (unsigned short*)(ws + (5u << 20));                // 8 MB

    kATT<<<1032, 256, 0, stream>>>(x, ln_mia_g, ln_mia_b, Wv, Vb,
                                   W1, W1t, W2, W2t, Wo, Wob);
    kB<<<4096, 256, 0, stream>>>(x, (const float4*)U1, mask, (const ushort4*)Vb,
                                 Wob, ln_ffn_g, ln_ffn_b, b2, out, xn2b);
    kC2m<<<dim3(16, 32), 256, 0, stream>>>(xn2b, W1t, b1, Aact);
    kC3m<<<dim3(4, 64, 2), 256, 0, stream>>>(Aact, W2t, out);
}